// Round 6
// baseline (7838.679 us; speedup 1.0000x reference)
//
#include <hip/hip_runtime.h>

#define HID 1024
#define FEAT 128
#define BAT 128
#define NSAMP 96
#define NPRED 8
#define GD 4096                    // 4*HID
#define SLOTE ((size_t)BAT * HID)  // 131072 elements per 128-row state slot
#define PREDT 16384                // elements per pred tile (2 chunk-groups)
#define CHUNK 8192                 // elements per 64-K chunk-group (16KB)

typedef unsigned short u16;
typedef unsigned int u32;
typedef unsigned long long u64;
typedef short bf16x8 __attribute__((ext_vector_type(8)));
typedef float f32x4 __attribute__((ext_vector_type(4)));

__device__ inline u16 f2bf(float f) {
    unsigned u = __float_as_uint(f);
    u += 0x7FFFu + ((u >> 16) & 1u);
    return (u16)(u >> 16);
}
__device__ inline float bf2f(u16 h) { return __uint_as_float(((unsigned)h) << 16); }
__device__ inline float fsig(float x) { return 1.0f / (1.0f + __expf(-x)); }
__device__ inline float ftanh(float x) { return 1.0f - 2.0f / (__expf(2.0f * x) + 1.0f); }

// ---------------------------------------------------------------------
// Fragment-major (FM) layout: a [128 rows][K] operand is stored so that
// one 64-K chunk-group (8192 elems = 16KB) is 16 x 1KB chunks, chunk
// c = h2*8 + i*2 + p, and within a chunk lane l = kq*16 + lc holds 16B:
//   element(row = h2*64 + i*16 + lc,  k = 64*g + p*32 + kq*8 + e)
// global_load_lds stages it as a LINEAR chunk copy (no ds_writes); an
// MFMA wave's fragment read is base + lane*16B -> zero bank conflicts.
// ---------------------------------------------------------------------
__device__ inline size_t fmoff(int row, int kk) {
    return (size_t)(kk >> 6) * CHUNK + (size_t)(row >> 6) * 4096
         + (size_t)((row >> 4) & 3) * 1024 + (size_t)((kk >> 5) & 1) * 512
         + (size_t)((kk >> 3) & 3) * 128 + (size_t)(row & 15) * 8 + (kk & 7);
}

__device__ inline void gl2lds16(const u16* g, u16* l) {
    __builtin_amdgcn_global_load_lds(
        (const __attribute__((address_space(1))) u32*)g,
        (__attribute__((address_space(3))) u32*)l, 16, 0, 0);
}

// Write-through agent-scope relaxed atomic 8B store: acks from the
// coherence point, never dirty in any L2.
__device__ inline void cstore8(u16* p, u64 v) {
    __hip_atomic_store((__attribute__((address_space(1))) u64*)p, v,
                       __ATOMIC_RELAXED, __HIP_MEMORY_SCOPE_AGENT);
}

__device__ inline u64 pack4bf(u16 a, u16 b, u16 c, u16 d) {
    return (u64)a | ((u64)b << 16) | ((u64)c << 32) | ((u64)d << 48);
}

// ---- per-block flags: word (l,step,b) at ((l*97+step)*32+b)*32 ints ----
#define FLAGN (2 * 97 * 32 * 32)
__device__ inline void waitset(const int* base) {
    const int tid = threadIdx.x;
    if (tid < 64) {
        long t = 0;
        for (;;) {
            int v = (tid < 32)
                ? __hip_atomic_load(base + tid * 32, __ATOMIC_RELAXED, __HIP_MEMORY_SCOPE_AGENT)
                : 1;
            if (__all(v != 0)) break;
            __builtin_amdgcn_s_sleep(2);
            if (++t > 3000000L) break;   // bounded: fail loud (wrong answer), not hang
        }
    }
    __builtin_amdgcn_fence(__ATOMIC_ACQUIRE, "workgroup");
    __syncthreads();   // also drains vmcnt(0): pre-issued DMAs land here
}

// panel q (32-K) of a FM tile: 8 strided 1KB chunks; wave stages chunks
// cp = wave*2 + c2 (cp = h2*4+i), global chunk c = (cp>>2)*8+(cp&3)*2+(q&1)
__device__ inline size_t pgoff(int q, int cp, int lane) {
    return (size_t)(q >> 1) * CHUNK
         + (size_t)(((cp >> 2) * 8) + ((cp & 3) * 2) + (q & 1)) * 512 + lane * 8;
}

// Phase-A LDS: 4 x (8KB A panel + 8KB B panel) = 64KB; sG aliases.
union SMemA {
    u16 st[4][2][4096];   // [buf][0=A,1=B][panel elems]
    float g[32][132];
};

// =====================================================================
// Phase A: persistent 2-layer filter chain. 64 blocks: b<32 -> L0 panel
// b; b>=32 -> L1. NEW: depth-3 counted-vmcnt panel pipeline (4 bufs,
// 32-K panels, vmcnt(8) steady state, never 0 in-loop). Flag-free /
// flag-held panels pre-issued before the spin (waitset's drain lands
// them; loop enters with 3 full buffers, counted waits exact from q=3).
// =====================================================================
__global__ __launch_bounds__(256, 1) void lstm_chain(
    const u16* __restrict__ inb,
    const u16* __restrict__ Wih0p, const u16* __restrict__ Whh0p,
    const u16* __restrict__ Wih1p, const u16* __restrict__ Whh1p,
    const float* __restrict__ bp0, const float* __restrict__ bp1,
    const float* __restrict__ c0,
    u16* __restrict__ chainH, u16* __restrict__ chainCb,
    float* __restrict__ h_std, float* __restrict__ c_std,
    int* __restrict__ flags)
{
    __shared__ SMemA sm;
    const int blk = blockIdx.x;
    const int l = blk >> 5, tn = blk & 31;
    const int tid = threadIdx.x;
    const int wave = tid >> 6, lane = tid & 63;
    const int wm = wave >> 1, wn = wave & 1;
    const int quad = lane >> 4, lc = lane & 15;
    const int rl = tid >> 3, ub = (tid & 7) * 4;

    const u16* BihS = (l ? Wih1p : Wih0p) + (size_t)tn * 128 * (l ? HID : FEAT);
    const u16* BhhS = (l ? Whh1p : Whh0p) + (size_t)tn * 128 * HID;
    const float* bias = l ? bp1 : bp0;
    auto fw = [&](int ll, int s) { return flags + ((size_t)(ll * 97 + s) * 32) * 32; };

    float creg[4][4];
#pragma unroll
    for (int i = 0; i < 4; ++i) {
        int lrow = (rl >> 4) * 64 + i * 16 + (rl & 15);
        float4 c4 = *(const float4*)(c0 + (size_t)l * SLOTE + (size_t)lrow * HID + tn * 32 + ub);
        creg[i][0] = c4.x; creg[i][1] = c4.y; creg[i][2] = c4.z; creg[i][3] = c4.w;
    }
    float bv[4];
#pragma unroll
    for (int j = 0; j < 4; ++j) bv[j] = bias[tn * 128 + wn * 64 + j * 16 + lc];

    const int frA = wm * 2048 + (quad * 16 + lc) * 8;   // + i*512 (panel-packed)
    const int frB = wn * 2048 + (quad * 16 + lc) * 8;   // + j*512

    for (int k = 0; k < NSAMP; ++k) {
        const int rk = (k <= 1) ? 0 : k;

        const u16 *A0, *B0, *A1s, *B1s; int KP0, NP;
        if (l == 0) {
            A0 = inb + (size_t)k * PREDT;              B0 = BihS; KP0 = 4;
            A1s = chainH + (size_t)rk * SLOTE;         B1s = BhhS; NP = 36;
        } else {
            A0 = chainH + (size_t)(k + 1) * SLOTE;     B0 = BihS; KP0 = 32;
            A1s = chainH + (size_t)(97 + rk) * SLOTE;  B1s = BhhS; NP = 64;
        }
        auto issue = [&](int q, int buf) {
            const u16 *Ab, *Bb; int qq;
            if (q < KP0) { Ab = A0;  Bb = B0;  qq = q; }
            else         { Ab = A1s; Bb = B1s; qq = q - KP0; }
#pragma unroll
            for (int c2 = 0; c2 < 2; ++c2) {
                int cp = wave * 2 + c2;
                size_t go = pgoff(qq, cp, lane);
                gl2lds16(Ab + go, &sm.st[buf][0][cp * 512]);
                gl2lds16(Bb + go, &sm.st[buf][1][cp * 512]);
            }
        };

        // prologue: 3 panels whose flags are already held / not needed;
        // latency hides under the flag spin, waitset's drain lands them.
        if (l == 0) {
            issue(0, 0); issue(1, 1); issue(2, 2);     // ih seg: flag-free
            waitset(fw(0, rk));
        } else {
            waitset(fw(0, k + 1));
            issue(0, 0); issue(1, 1); issue(2, 2);     // ih seg: flag held
            waitset(fw(1, rk));
        }

        f32x4 acc[4][4];
#pragma unroll
        for (int j = 0; j < 4; ++j) {
            f32x4 bvv = {bv[j], bv[j], bv[j], bv[j]};
#pragma unroll
            for (int i = 0; i < 4; ++i) acc[i][j] = bvv;
        }

        for (int q = 0; q < NP; ++q) {
            // panel q landed; q+1,q+2 may stay in flight (4 DMAs/wave/panel)
            if (q + 2 < NP)      asm volatile("s_waitcnt vmcnt(8)" ::: "memory");
            else if (q + 1 < NP) asm volatile("s_waitcnt vmcnt(4)" ::: "memory");
            else                 asm volatile("s_waitcnt vmcnt(0)" ::: "memory");
            __builtin_amdgcn_s_barrier();    // all waves: q landed + done MFMA(q-1)
            __builtin_amdgcn_sched_barrier(0);
            if (q + 3 < NP) issue(q + 3, (q + 3) & 3);
            const u16* la = sm.st[q & 3][0];
            const u16* lb = sm.st[q & 3][1];
            bf16x8 aF[4], bF[4];
#pragma unroll
            for (int i = 0; i < 4; ++i)
                aF[i] = *(const bf16x8*)&la[frA + i * 512];
#pragma unroll
            for (int j = 0; j < 4; ++j)
                bF[j] = *(const bf16x8*)&lb[frB + j * 512];
#pragma unroll
            for (int i = 0; i < 4; ++i)
#pragma unroll
                for (int j = 0; j < 4; ++j)
                    acc[i][j] = __builtin_amdgcn_mfma_f32_16x16x32_bf16(aF[i], bF[j], acc[i][j], 0, 0, 0);
        }

        __syncthreads();   // sG aliases staging buffers
        size_t slotBase = (size_t)(l * 97 + k + 1) * SLOTE;
#pragma unroll 1
        for (int i = 0; i < 4; ++i) {
#pragma unroll
            for (int j = 0; j < 4; ++j)
#pragma unroll
                for (int r = 0; r < 4; ++r)
                    sm.g[wm * 16 + quad * 4 + r][wn * 64 + j * 16 + lc] = acc[i][j][r];
            __syncthreads();
            int lrow = (rl >> 4) * 64 + i * 16 + (rl & 15);
            float c2v[4], h2v[4];
#pragma unroll
            for (int uu = 0; uu < 4; ++uu) {
                float4 gg = *(const float4*)&sm.g[rl][(ub + uu) * 4];
                float iv = fsig(gg.x), fv = fsig(gg.y), gv = ftanh(gg.z), ov = fsig(gg.w);
                float c2 = fv * creg[i][uu] + iv * gv;
                if (k != 0) creg[i][uu] = c2;    // filter update only for k>=1
                c2v[uu] = c2;
                h2v[uu] = ov * ftanh(c2);
            }
            cstore8(chainH + slotBase + fmoff(lrow, tn * 32 + ub),
                    pack4bf(f2bf(h2v[0]), f2bf(h2v[1]), f2bf(h2v[2]), f2bf(h2v[3])));
            size_t pOff = slotBase + ((size_t)tn * 128 + lrow) * 32 + ub;
            *(ushort4*)(chainCb + pOff) =
                make_ushort4(f2bf(c2v[0]), f2bf(c2v[1]), f2bf(c2v[2]), f2bf(c2v[3]));
            if (k == 95) {
                size_t sOff = (size_t)l * SLOTE + (size_t)lrow * HID + tn * 32 + ub;
                *(float4*)(h_std + sOff) = make_float4(h2v[0], h2v[1], h2v[2], h2v[3]);
                *(float4*)(c_std + sOff) = make_float4(c2v[0], c2v[1], c2v[2], c2v[3]);
            }
            __syncthreads();   // drains vmcnt(0): all stores at coherence point
        }
        if (tid == 0)
            __hip_atomic_store((__attribute__((address_space(1))) int*)(fw(l, k + 1) + tn * 32),
                               1, __ATOMIC_RELAXED, __HIP_MEMORY_SCOPE_AGENT);
    }
}

// =====================================================================
// Phase B: GEMM+LSTM / GEMM+linear. 3-buffer 2-deep counted-vmcnt
// prefetch pipeline over 32-K panels (unchanged from round 5).
// =====================================================================
struct GArgs {
    const u16* A1; const u16* A2;
    const u16 *B1, *B2;
    const float* bias;
    const u16* c_in; u16* cout_b;
    u16* h_out;
    u16* lin_out;
    int KP1, KP2;          // panels (K/32) per seg; 0 = absent
    int as1, as2;          // A tile stride (elements)
    int mode;
};

// Phase-B LDS: 3 x (8KB A panel + 8KB B panel) = 48KB; sG aliases.
union SMemB {
    u16 st[3][2][4096];
    float g[32][132];
};

// persistent LSTM-step GEMM: 768 blocks (3/CU), tn=bx&31, 4 tm tiles each
__global__ __launch_bounds__(256, 3) void gemm_lstm(GArgs g)
{
    __shared__ SMemB sm;
    const int tid = threadIdx.x;
    const int wave = tid >> 6, lane = tid & 63;
    const int wm = wave >> 1, wn = wave & 1;
    const int quad = lane >> 4, lc = lane & 15;
    const int tn = blockIdx.x & 31;
    const int tm0 = (blockIdx.x >> 5) * 4;
    const int frA = wm * 2048 + (quad * 16 + lc) * 8;   // + i*512 (panel-packed)
    const int frB = wn * 2048 + (quad * 16 + lc) * 8;   // + j*512

    const u16* B1p = g.B1 + (size_t)tn * g.KP1 * 4096;
    const u16* B2p = g.B2 + (size_t)tn * g.KP2 * 4096;
    const int NP = g.KP1 + g.KP2;

    for (int t = 0; t < 4; ++t) {
        const int tm = tm0 + t;
        const u16* A1t = g.A1 + (size_t)tm * g.as1;
        const u16* A2t = g.A2 + (size_t)tm * g.as2;

        auto issue = [&](int q, int buf) {
            const u16 *Ab, *Bb; int qq;
            if (q < g.KP1) { Ab = A1t; Bb = B1p; qq = q; }
            else           { Ab = A2t; Bb = B2p; qq = q - g.KP1; }
#pragma unroll
            for (int c2 = 0; c2 < 2; ++c2) {
                int cp = wave * 2 + c2;
                size_t go = pgoff(qq, cp, lane);
                gl2lds16(Ab + go, &sm.st[buf][0][cp * 512]);
                gl2lds16(Bb + go, &sm.st[buf][1][cp * 512]);
            }
        };

        f32x4 acc[4][4];
#pragma unroll
        for (int j = 0; j < 4; ++j) {
            float bvx = g.bias[tn * 128 + wn * 64 + j * 16 + lc];
            f32x4 bvv = {bvx, bvx, bvx, bvx};
#pragma unroll
            for (int i = 0; i < 4; ++i) acc[i][j] = bvv;
        }

        issue(0, 0);
        issue(1, 1);
        for (int q = 0; q < NP; ++q) {
            if (q + 1 < NP) asm volatile("s_waitcnt vmcnt(4)" ::: "memory");
            else            asm volatile("s_waitcnt vmcnt(0)" ::: "memory");
            __builtin_amdgcn_s_barrier();    // all waves: landed + done MFMA(q-1)
            __builtin_amdgcn_sched_barrier(0);
            if (q + 2 < NP) issue(q + 2, (q + 2) % 3);
            const u16* la = sm.st[q % 3][0];
            const u16* lb = sm.st[q % 3][1];
            bf16x8 aF[4], bF[4];
#pragma unroll
            for (int i = 0; i < 4; ++i)
                aF[i] = *(const bf16x8*)&la[frA + i * 512];
#pragma unroll
            for (int j = 0; j < 4; ++j)
                bF[j] = *(const bf16x8*)&lb[frB + j * 512];
#pragma unroll
            for (int i = 0; i < 4; ++i)
#pragma unroll
                for (int j = 0; j < 4; ++j)
                    acc[i][j] = __builtin_amdgcn_mfma_f32_16x16x32_bf16(aF[i], bF[j], acc[i][j], 0, 0, 0);
        }
        __syncthreads();   // all MFMA reads done; sG (aliases st) now writable

        const int rl = tid >> 3, ub = (tid & 7) * 4;
#pragma unroll 1
        for (int i = 0; i < 4; ++i) {
#pragma unroll
            for (int j = 0; j < 4; ++j)
#pragma unroll
                for (int r = 0; r < 4; ++r)
                    sm.g[wm * 16 + quad * 4 + r][wn * 64 + j * 16 + lc] = acc[i][j][r];
            __syncthreads();
            int lrow = (rl >> 4) * 64 + i * 16 + (rl & 15);
            size_t pOff = (size_t)tm * SLOTE + ((size_t)tn * 128 + lrow) * 32 + ub;
            ushort4 co = *(const ushort4*)(g.c_in + pOff);
            float cold[4] = {bf2f(co.x), bf2f(co.y), bf2f(co.z), bf2f(co.w)};
            float c2v[4], h2v[4];
#pragma unroll
            for (int uu = 0; uu < 4; ++uu) {
                float4 gg = *(const float4*)&sm.g[rl][(ub + uu) * 4];
                float iv = fsig(gg.x), fv = fsig(gg.y), gv = ftanh(gg.z), ov = fsig(gg.w);
                float c2 = fv * cold[uu] + iv * gv;
                c2v[uu] = c2;
                h2v[uu] = ov * ftanh(c2);
            }
            *(ushort4*)(g.cout_b + pOff) =
                make_ushort4(f2bf(c2v[0]), f2bf(c2v[1]), f2bf(c2v[2]), f2bf(c2v[3]));
            *(ushort4*)(g.h_out + (size_t)tm * SLOTE + fmoff(lrow, tn * 32 + ub)) =
                make_ushort4(f2bf(h2v[0]), f2bf(h2v[1]), f2bf(h2v[2]), f2bf(h2v[3]));
            __syncthreads();
        }
    }
}

// linear-head GEMM: grid = 96 blocks (one per sample tile), tn = 0
__global__ __launch_bounds__(256, 3) void gemm_lin(GArgs g)
{
    __shared__ u16 st[3][2][4096];
    const int tid = threadIdx.x;
    const int wave = tid >> 6, lane = tid & 63;
    const int wm = wave >> 1, wn = wave & 1;
    const int quad = lane >> 4, lc = lane & 15;
    const int tm = blockIdx.x;
    const int frA = wm * 2048 + (quad * 16 + lc) * 8;
    const int frB = wn * 2048 + (quad * 16 + lc) * 8;

    const u16* A1t = g.A1 + (size_t)tm * g.as1;
    const int NP = g.KP1;

    auto issue = [&](int q, int buf) {
#pragma unroll
        for (int c2 = 0; c2 < 2; ++c2) {
            int cp = wave * 2 + c2;
            size_t go = pgoff(q, cp, lane);
            gl2lds16(A1t + go, &st[buf][0][cp * 512]);
            gl2lds16(g.B1 + go, &st[buf][1][cp * 512]);
        }
    };

    f32x4 acc[4][4];
#pragma unroll
    for (int j = 0; j < 4; ++j) {
        float bvx = g.bias[wn * 64 + j * 16 + lc];
        f32x4 bvv = {bvx, bvx, bvx, bvx};
#pragma unroll
        for (int i = 0; i < 4; ++i) acc[i][j] = bvv;
    }

    issue(0, 0);
    issue(1, 1);
    for (int q = 0; q < NP; ++q) {
        if (q + 1 < NP) asm volatile("s_waitcnt vmcnt(4)" ::: "memory");
        else            asm volatile("s_waitcnt vmcnt(0)" ::: "memory");
        __builtin_amdgcn_s_barrier();
        __builtin_amdgcn_sched_barrier(0);
        if (q + 2 < NP) issue(q + 2, (q + 2) % 3);
        const u16* la = st[q % 3][0];
        const u16* lb = st[q % 3][1];
        bf16x8 aF[4], bF[4];
#pragma unroll
        for (int i = 0; i < 4; ++i)
            aF[i] = *(const bf16x8*)&la[frA + i * 512];
#pragma unroll
        for (int j = 0; j < 4; ++j)
            bF[j] = *(const bf16x8*)&lb[frB + j * 512];
#pragma unroll
        for (int i = 0; i < 4; ++i)
#pragma unroll
            for (int j = 0; j < 4; ++j)
                acc[i][j] = __builtin_amdgcn_mfma_f32_16x16x32_bf16(aF[i], bF[j], acc[i][j], 0, 0, 0);
    }

    // pred tile in FM layout
#pragma unroll
    for (int i = 0; i < 4; ++i)
#pragma unroll
        for (int j = 0; j < 4; ++j)
#pragma unroll
            for (int r = 0; r < 4; ++r) {
                int grow = wm * 64 + i * 16 + quad * 4 + r;
                int gcol = wn * 64 + j * 16 + lc;
                g.lin_out[(size_t)tm * PREDT + fmoff(grow, gcol)] = f2bf(acc[i][j][r]);
            }
}

// ---- setup / epilogue kernels ----
__global__ void convert_weight(const float* __restrict__ src, u16* __restrict__ dst,
                               int kshift, int permute, int total) {
    int idx = blockIdx.x * 256 + threadIdx.x;
    if (idx >= total) return;
    const int K = 1 << kshift;
    int kk = idx & (K - 1);
    int rr = (idx >> kshift) & 127;
    int s = idx >> (kshift + 7);
    int jp = s * 128 + rr;
    int srow = permute ? ((jp & 3) * HID + (jp >> 2)) : jp;
    dst[((size_t)s << (kshift + 7)) + fmoff(rr, kk)] =
        f2bf(src[((size_t)srow << kshift) + kk]);
}

__global__ void conv_input(const float* __restrict__ in, u16* __restrict__ inb) {
    int idx = blockIdx.x * 256 + threadIdx.x;  // 96*128*128
    int f = idx & 127;
    int b = (idx >> 7) & 127;
    int k = idx >> 14;
    inb[(size_t)k * PREDT + fmoff(b, f)] = f2bf(in[idx]);
}

__global__ void combine_bias(const float* __restrict__ bi, const float* __restrict__ bh,
                             float* __restrict__ dst) {
    int j = blockIdx.x * 256 + threadIdx.x;  // 4096
    int s = (j & 3) * HID + (j >> 2);
    dst[j] = bi[s] + bh[s];
}

__global__ void init_state(const float* __restrict__ h0, u16* __restrict__ chainH) {
    int idx = blockIdx.x * 256 + threadIdx.x;  // 2*BAT*HID
    int l = idx >> 17;
    int r = idx & (int)(SLOTE - 1);
    int b = r >> 10, hh = r & 1023;
    chainH[(size_t)l * 97 * SLOTE + fmoff(b, hh)] = f2bf(h0[idx]);
}

__global__ void init_flags(int* __restrict__ f) {
    int gid = blockIdx.x * 256 + threadIdx.x;
    if (gid >= FLAGN) return;
    int step = (gid >> 10) % 97;             // flag word stride 32 ints; 32 blocks/step
    f[gid] = ((gid & 31) == 0 && step == 0) ? 1 : 0;
}

__global__ void copy_next(const u16* __restrict__ predsb, float* __restrict__ out) {
    int idx = blockIdx.x * 256 + threadIdx.x;  // BAT*FEAT
    int b = idx >> 7, f = idx & 127;
    out[idx] = bf2f(predsb[(size_t)95 * PREDT + fmoff(b, f)]);
}

__global__ void gather_out(const float* __restrict__ inMusic, const u16* __restrict__ predsb,
                           float* __restrict__ outM) {
    int idx = blockIdx.x * 256 + threadIdx.x;  // 96*128*128*8
    int n = idx & 7;
    int f = (idx >> 3) & 127;
    int b = (idx >> 10) & 127;
    int r = idx >> 17;
    float v = 0.0f;
    if (r < NPRED && n >= r) {
        v = inMusic[((size_t)r * BAT + b) * FEAT + f];
    } else {
        int k = r - n - 1;
        if (n < k)
            v = bf2f(predsb[((size_t)n * NSAMP + k) * PREDT + fmoff(b, f)]);
    }
    outM[idx] = v;
}

__global__ void zero_out(float* __restrict__ o, int nmax) {
    int idx = blockIdx.x * 256 + threadIdx.x;
    if (idx < nmax) o[idx] = 0.0f;
}

extern "C" void kernel_launch(void* const* d_in, const int* in_sizes, int n_in,
                              void* d_out, int out_size, void* d_ws, size_t ws_size,
                              hipStream_t stream) {
    (void)in_sizes; (void)n_in;
    const float* inMusic = (const float*)d_in[0];
    const float* h0   = (const float*)d_in[1];
    const float* c0   = (const float*)d_in[2];
    const float* Wih0 = (const float*)d_in[3];
    const float* Whh0 = (const float*)d_in[4];
    const float* bih0 = (const float*)d_in[5];
    const float* bhh0 = (const float*)d_in[6];
    const float* Wih1 = (const float*)d_in[7];
    const float* Whh1 = (const float*)d_in[8];
    const float* bih1 = (const float*)d_in[9];
    const float* bhh1 = (const float*)d_in[10];
    const float* Wlin = (const float*)d_in[11];
    const float* blin = (const float*)d_in[12];
    float* out = (float*)d_out;

    const size_t OUT_H = (size_t)NSAMP * BAT * FEAT * NPRED;
    const size_t OUT_C = OUT_H + 2 * SLOTE;
    const size_t OUT_NEXT = OUT_C + 2 * SLOTE;

    char* ws = (char*)d_ws;
    size_t off = 0;
    auto alloc = [&](size_t bytes) {
        void* p = ws + off;
        off = (off + bytes + 255) & ~(size_t)255;
        return p;
    };
    u16* Wih0p = (u16*)alloc((size_t)GD * FEAT * 2);
    u16* Whh0p = (u16*)alloc((size_t)GD * HID * 2);
    u16* Wih1p = (u16*)alloc((size_t)GD * HID * 2);
    u16* Whh1p = (u16*)alloc((size_t)GD * HID * 2);
    u16* Wlinb = (u16*)alloc((size_t)FEAT * HID * 2);
    float* bp0 = (float*)alloc(GD * 4);
    float* bp1 = (float*)alloc(GD * 4);
    u16* chainH  = (u16*)alloc((size_t)2 * 97 * SLOTE * 2);
    u16* chainCb = (u16*)alloc((size_t)2 * 97 * SLOTE * 2);
    u16* hp2 = (u16*)alloc((size_t)2 * (size_t)NSAMP * SLOTE * 2);
    u16* predsb = (u16*)alloc((size_t)NPRED * NSAMP * PREDT * 2);
    u16* inb = (u16*)alloc((size_t)NSAMP * PREDT * 2);
    int* flags = (int*)alloc((size_t)FLAGN * 4);

    if (off > ws_size) {
        zero_out<<<(out_size + 255) / 256, 256, 0, stream>>>(out, out_size);
        return;
    }

    convert_weight<<<(GD * FEAT + 255) / 256, 256, 0, stream>>>(Wih0, Wih0p, 7, 1, GD * FEAT);
    convert_weight<<<(GD * HID + 255) / 256, 256, 0, stream>>>(Whh0, Whh0p, 10, 1, GD * HID);
    convert_weight<<<(GD * HID + 255) / 256, 256, 0, stream>>>(Wih1, Wih1p, 10, 1, GD * HID);
    convert_weight<<<(GD * HID + 255) / 256, 256, 0, stream>>>(Whh1, Whh1p, 10, 1, GD * HID);
    convert_weight<<<(FEAT * HID + 255) / 256, 256, 0, stream>>>(Wlin, Wlinb, 10, 0, FEAT * HID);
    conv_input<<<(NSAMP * BAT * FEAT) / 256, 256, 0, stream>>>(inMusic, inb);
    combine_bias<<<GD / 256, 256, 0, stream>>>(bih0, bhh0, bp0);
    combine_bias<<<GD / 256, 256, 0, stream>>>(bih1, bhh1, bp1);
    init_state<<<(int)(2 * SLOTE) / 256, 256, 0, stream>>>(h0, chainH);
    init_flags<<<(FLAGN + 255) / 256, 256, 0, stream>>>(flags);

    lstm_chain<<<64, 256, 0, stream>>>(
        inb, Wih0p, Whh0p, Wih1p, Whh1p, bp0, bp1, c0,
        chainH, chainCb, out + OUT_H, out + OUT_C, flags);

    auto Hs = [&](int l, int s) { return chainH + ((size_t)l * 97 + s) * SLOTE; };
    auto Cs = [&](int l, int s) { return chainCb + ((size_t)l * 97 + s) * SLOTE; };

    u16* hbuf0[2] = {Hs(0, 1), Hs(1, 1)};
    u16* hbuf1[2] = {hp2, hp2 + (size_t)NSAMP * SLOTE};
    u16* cB[2] = {Cs(0, 1), Cs(1, 1)};

    auto mkLin = [&](const u16* src, u16* dst) {
        GArgs a = {};
        a.A1 = src; a.KP1 = 32; a.as1 = (int)SLOTE; a.KP2 = 0;
        a.B1 = Wlinb; a.bias = blin;
        a.lin_out = dst; a.mode = 1;
        return a;
    };
    auto mkB = [&](int l, const u16* A1, int kp1, int as1, const u16* A2, u16* nxt) {
        GArgs a = {};
        a.A1 = A1; a.KP1 = kp1; a.as1 = as1;
        a.A2 = A2; a.KP2 = 32; a.as2 = (int)SLOTE;
        a.B1 = (l == 0) ? Wih0p : Wih1p; a.B2 = (l == 0) ? Whh0p : Whh1p;
        a.bias = (l == 0) ? bp0 : bp1;
        a.c_in = cB[l]; a.cout_b = cB[l];
        a.h_out = nxt; a.mode = 0;
        return a;
    };

    gemm_lin<<<96, 256, 0, stream>>>(mkLin(hbuf0[1], predsb));
    copy_next<<<(BAT * FEAT) / 256, 256, 0, stream>>>(predsb, out + OUT_NEXT);

    for (int n = 1; n < NPRED; ++n) {
        u16* cur0 = (n & 1) ? hbuf0[0] : hbuf1[0];
        u16* cur1 = (n & 1) ? hbuf0[1] : hbuf1[1];
        u16* nxt0 = (n & 1) ? hbuf1[0] : hbuf0[0];
        u16* nxt1 = (n & 1) ? hbuf1[1] : hbuf0[1];
        const u16* pin = predsb + (size_t)(n - 1) * NSAMP * PREDT;
        u16* pout = predsb + (size_t)n * NSAMP * PREDT;
        gemm_lstm<<<768, 256, 0, stream>>>(mkB(0, pin, 4, PREDT, cur0, nxt0));
        gemm_lstm<<<768, 256, 0, stream>>>(mkB(1, nxt0, 32, (int)SLOTE, cur1, nxt1));
        gemm_lin<<<96, 256, 0, stream>>>(mkLin(nxt1, pout));
    }

    gather_out<<<(NSAMP * BAT * FEAT * NPRED) / 256, 256, 0, stream>>>(inMusic, predsb, out);
}

// Round 7
// 7707.555 us; speedup vs baseline: 1.0170x; 1.0170x over previous
//
#include <hip/hip_runtime.h>

#define HID 1024
#define FEAT 128
#define BAT 128
#define NSAMP 96
#define NPRED 8
#define GD 4096                    // 4*HID
#define SLOTE ((size_t)BAT * HID)  // 131072 elements per 128-row state slot
#define PREDT 16384                // elements per pred tile (2 chunk-groups)
#define CHUNK 8192                 // elements per 64-K chunk-group (16KB)

typedef unsigned short u16;
typedef unsigned int u32;
typedef unsigned long long u64;
typedef short bf16x8 __attribute__((ext_vector_type(8)));
typedef float f32x4 __attribute__((ext_vector_type(4)));

__device__ inline u16 f2bf(float f) {
    unsigned u = __float_as_uint(f);
    u += 0x7FFFu + ((u >> 16) & 1u);
    return (u16)(u >> 16);
}
__device__ inline float bf2f(u16 h) { return __uint_as_float(((unsigned)h) << 16); }
__device__ inline float fsig(float x) { return 1.0f / (1.0f + __expf(-x)); }
__device__ inline float ftanh(float x) { return 1.0f - 2.0f / (__expf(2.0f * x) + 1.0f); }

// ---------------------------------------------------------------------
// Fragment-major (FM) layout: a [128 rows][K] operand is stored so that
// one 64-K chunk-group (8192 elems = 16KB) is 16 x 1KB chunks, chunk
// c = h2*8 + i*2 + p, and within a chunk lane l = kq*16 + lc holds 16B:
//   element(row = h2*64 + i*16 + lc,  k = 64*g + p*32 + kq*8 + e)
// global_load_lds stages it as a LINEAR chunk copy (no ds_writes); an
// MFMA wave's fragment read is base + lane*16B -> zero bank conflicts.
// ---------------------------------------------------------------------
__device__ inline size_t fmoff(int row, int kk) {
    return (size_t)(kk >> 6) * CHUNK + (size_t)(row >> 6) * 4096
         + (size_t)((row >> 4) & 3) * 1024 + (size_t)((kk >> 5) & 1) * 512
         + (size_t)((kk >> 3) & 3) * 128 + (size_t)(row & 15) * 8 + (kk & 7);
}

__device__ inline void gl2lds16(const u16* g, u16* l) {
    __builtin_amdgcn_global_load_lds(
        (const __attribute__((address_space(1))) u32*)g,
        (__attribute__((address_space(3))) u32*)l, 16, 0, 0);
}

// Write-through agent-scope relaxed atomic 8B store: acks from the
// coherence point, never dirty in any L2.
__device__ inline void cstore8(u16* p, u64 v) {
    __hip_atomic_store((__attribute__((address_space(1))) u64*)p, v,
                       __ATOMIC_RELAXED, __HIP_MEMORY_SCOPE_AGENT);
}

__device__ inline u64 pack4bf(u16 a, u16 b, u16 c, u16 d) {
    return (u64)a | ((u64)b << 16) | ((u64)c << 32) | ((u64)d << 48);
}

// ---- per-block flags: word (l,step,b) at ((l*97+step)*32+b)*32 ints ----
#define FLAGN (2 * 97 * 32 * 32)
// Drain-free flag wait: wave0 polls (agent-scope L2-bypass loads), raw
// s_barrier holds the other waves, sched_barrier pins compiler ordering.
// No vmcnt(0)/fence: post-poll data reads are first-touch this dispatch
// (L1/L2 start clean; producers write through to L3), and instruction
// issue is in-order after the data-dependent poll branch.
__device__ inline void pollflag(const int* base) {
    const int tid = threadIdx.x;
    if (tid < 64) {
        long t = 0;
        for (;;) {
            int v = (tid < 32)
                ? __hip_atomic_load(base + tid * 32, __ATOMIC_RELAXED, __HIP_MEMORY_SCOPE_AGENT)
                : 1;
            if (__all(v != 0)) break;
            __builtin_amdgcn_s_sleep(1);
            if (++t > 3000000L) break;   // bounded: fail loud (wrong answer), not hang
        }
    }
    __builtin_amdgcn_s_barrier();
    __builtin_amdgcn_sched_barrier(0);
}

// panel q (32-K) of a FM tile: 8 strided 1KB chunks; wave stages chunks
// cp = wave*2 + c2 (cp = h2*4+i), global chunk c = (cp>>2)*8+(cp&3)*2+(q&1)
__device__ inline size_t pgoff(int q, int cp, int lane) {
    return (size_t)(q >> 1) * CHUNK
         + (size_t)(((cp >> 2) * 8) + ((cp & 3) * 2) + (q & 1)) * 512 + lane * 8;
}

// Phase-A LDS: 4 x (8KB A panel + 8KB B panel) = 64KB; sG aliases.
union SMemA {
    u16 st[4][2][4096];   // [buf][0=A,1=B][panel elems]
    float g[32][132];
};

// =====================================================================
// Phase A: persistent 2-layer filter chain. 64 blocks: b<32 -> L0 panel
// b; b>=32 -> L1. Depth-3 counted-vmcnt panel pipeline (4 bufs).
// NEW this round:
//  - L1 computes its hh half FIRST (gated only on its own previous step),
//    and polls L0's flag MID-LOOP just before issuing the ih half ->
//    L0's completion overlaps 32 panels of L1 compute.
//  - L0 drops the upfront wait: ih panels are flag-free; its own flag is
//    polled mid-loop just before the first hh panel issue.
//  - Epilogue uses raw s_barriers (no per-iteration vmcnt(0) drains);
//    ONE vmcnt(0) drain before the flag store publishes everything.
// =====================================================================
__global__ __launch_bounds__(256, 1) void lstm_chain(
    const u16* __restrict__ inb,
    const u16* __restrict__ Wih0p, const u16* __restrict__ Whh0p,
    const u16* __restrict__ Wih1p, const u16* __restrict__ Whh1p,
    const float* __restrict__ bp0, const float* __restrict__ bp1,
    const float* __restrict__ c0,
    u16* __restrict__ chainH, u16* __restrict__ chainCb,
    float* __restrict__ h_std, float* __restrict__ c_std,
    int* __restrict__ flags)
{
    __shared__ SMemA sm;
    const int blk = blockIdx.x;
    const int l = blk >> 5, tn = blk & 31;
    const int tid = threadIdx.x;
    const int wave = tid >> 6, lane = tid & 63;
    const int wm = wave >> 1, wn = wave & 1;
    const int quad = lane >> 4, lc = lane & 15;
    const int rl = tid >> 3, ub = (tid & 7) * 4;

    const u16* BihS = (l ? Wih1p : Wih0p) + (size_t)tn * 128 * (l ? HID : FEAT);
    const u16* BhhS = (l ? Whh1p : Whh0p) + (size_t)tn * 128 * HID;
    const float* bias = l ? bp1 : bp0;
    auto fw = [&](int ll, int s) { return flags + ((size_t)(ll * 97 + s) * 32) * 32; };

    float creg[4][4];
#pragma unroll
    for (int i = 0; i < 4; ++i) {
        int lrow = (rl >> 4) * 64 + i * 16 + (rl & 15);
        float4 c4 = *(const float4*)(c0 + (size_t)l * SLOTE + (size_t)lrow * HID + tn * 32 + ub);
        creg[i][0] = c4.x; creg[i][1] = c4.y; creg[i][2] = c4.z; creg[i][3] = c4.w;
    }
    float bv[4];
#pragma unroll
    for (int j = 0; j < 4; ++j) bv[j] = bias[tn * 128 + wn * 64 + j * 16 + lc];

    const int frA = wm * 2048 + (quad * 16 + lc) * 8;   // + i*512 (panel-packed)
    const int frB = wn * 2048 + (quad * 16 + lc) * 8;   // + j*512

    for (int k = 0; k < NSAMP; ++k) {
        const int rk = (k <= 1) ? 0 : k;

        // seg0 = ungated-at-loop-entry panels; seg1 gated by `gate`,
        // polled mid-loop right before panel KP0 is issued.
        const u16 *A0, *B0, *A1s, *B1s; int KP0, NP; const int* gate;
        if (l == 0) {
            // seg0 = ih (input, flag-free); seg1 = hh (own h[k-1])
            A0 = inb + (size_t)k * PREDT;              B0 = BihS; KP0 = 4;
            A1s = chainH + (size_t)rk * SLOTE;         B1s = BhhS; NP = 36;
            gate = fw(0, rk);
        } else {
            // seg0 = hh (own h1[k-1], flag available ~immediately);
            // seg1 = ih (L0's h0 output of step k) gated on fw(0,k+1)
            pollflag(fw(1, rk));
            A0 = chainH + (size_t)(97 + rk) * SLOTE;   B0 = BhhS; KP0 = 32;
            A1s = chainH + (size_t)(k + 1) * SLOTE;    B1s = BihS; NP = 64;
            gate = fw(0, k + 1);
        }
        const int qgate = KP0 - 3;   // iteration whose issue target == KP0

        auto issue = [&](int q, int buf) {
            const u16 *Ab, *Bb; int qq;
            if (q < KP0) { Ab = A0;  Bb = B0;  qq = q; }
            else         { Ab = A1s; Bb = B1s; qq = q - KP0; }
#pragma unroll
            for (int c2 = 0; c2 < 2; ++c2) {
                int cp = wave * 2 + c2;
                size_t go = pgoff(qq, cp, lane);
                gl2lds16(Ab + go, &sm.st[buf][0][cp * 512]);
                gl2lds16(Bb + go, &sm.st[buf][1][cp * 512]);
            }
        };

        // prologue: 3 seg0 panels (no gate needed)
        issue(0, 0); issue(1, 1); issue(2, 2);

        f32x4 acc[4][4];
#pragma unroll
        for (int j = 0; j < 4; ++j) {
            f32x4 bvv = {bv[j], bv[j], bv[j], bv[j]};
#pragma unroll
            for (int i = 0; i < 4; ++i) acc[i][j] = bvv;
        }

        for (int q = 0; q < NP; ++q) {
            // panel q landed; q+1,q+2 may stay in flight (4 DMAs/wave/panel)
            if (q + 2 < NP)      asm volatile("s_waitcnt vmcnt(8)" ::: "memory");
            else if (q + 1 < NP) asm volatile("s_waitcnt vmcnt(4)" ::: "memory");
            else                 asm volatile("s_waitcnt vmcnt(0)" ::: "memory");
            __builtin_amdgcn_s_barrier();    // all waves: q landed + done MFMA(q-1)
            __builtin_amdgcn_sched_barrier(0);
            if (q == qgate) pollflag(gate);  // gate seg1 issues (one-time poll)
            if (q + 3 < NP) issue(q + 3, (q + 3) & 3);
            const u16* la = sm.st[q & 3][0];
            const u16* lb = sm.st[q & 3][1];
            bf16x8 aF[4], bF[4];
#pragma unroll
            for (int i = 0; i < 4; ++i)
                aF[i] = *(const bf16x8*)&la[frA + i * 512];
#pragma unroll
            for (int j = 0; j < 4; ++j)
                bF[j] = *(const bf16x8*)&lb[frB + j * 512];
#pragma unroll
            for (int i = 0; i < 4; ++i)
#pragma unroll
                for (int j = 0; j < 4; ++j)
                    acc[i][j] = __builtin_amdgcn_mfma_f32_16x16x32_bf16(aF[i], bF[j], acc[i][j], 0, 0, 0);
        }

        __syncthreads();   // sG aliases staging buffers; K-loop fully quiesced
        size_t slotBase = (size_t)(l * 97 + k + 1) * SLOTE;
#pragma unroll 1
        for (int i = 0; i < 4; ++i) {
#pragma unroll
            for (int j = 0; j < 4; ++j)
#pragma unroll
                for (int r = 0; r < 4; ++r)
                    sm.g[wm * 16 + quad * 4 + r][wn * 64 + j * 16 + lc] = acc[i][j][r];
            asm volatile("s_waitcnt lgkmcnt(0)" ::: "memory");  // own sG writes visible
            __builtin_amdgcn_s_barrier();                        // raw: no vmcnt drain
            __builtin_amdgcn_sched_barrier(0);
            int lrow = (rl >> 4) * 64 + i * 16 + (rl & 15);
            float c2v[4], h2v[4];
#pragma unroll
            for (int uu = 0; uu < 4; ++uu) {
                float4 gg = *(const float4*)&sm.g[rl][(ub + uu) * 4];
                float iv = fsig(gg.x), fv = fsig(gg.y), gv = ftanh(gg.z), ov = fsig(gg.w);
                float c2 = fv * creg[i][uu] + iv * gv;
                if (k != 0) creg[i][uu] = c2;    // filter update only for k>=1
                c2v[uu] = c2;
                h2v[uu] = ov * ftanh(c2);
            }
            cstore8(chainH + slotBase + fmoff(lrow, tn * 32 + ub),
                    pack4bf(f2bf(h2v[0]), f2bf(h2v[1]), f2bf(h2v[2]), f2bf(h2v[3])));
            size_t pOff = slotBase + ((size_t)tn * 128 + lrow) * 32 + ub;
            *(ushort4*)(chainCb + pOff) =
                make_ushort4(f2bf(c2v[0]), f2bf(c2v[1]), f2bf(c2v[2]), f2bf(c2v[3]));
            if (k == 95) {
                size_t sOff = (size_t)l * SLOTE + (size_t)lrow * HID + tn * 32 + ub;
                *(float4*)(h_std + sOff) = make_float4(h2v[0], h2v[1], h2v[2], h2v[3]);
                *(float4*)(c_std + sOff) = make_float4(c2v[0], c2v[1], c2v[2], c2v[3]);
            }
            // raw barrier: WAR guard for next iteration's sG writes; the
            // global stores continue draining in the background.
            __builtin_amdgcn_s_barrier();
            __builtin_amdgcn_sched_barrier(0);
        }
        // single publish point: each wave drains its own stores to the
        // coherence point, barrier, then one relaxed flag store.
        asm volatile("s_waitcnt vmcnt(0)" ::: "memory");
        __builtin_amdgcn_s_barrier();
        if (tid == 0)
            __hip_atomic_store((__attribute__((address_space(1))) int*)(fw(l, k + 1) + tn * 32),
                               1, __ATOMIC_RELAXED, __HIP_MEMORY_SCOPE_AGENT);
    }
}

// =====================================================================
// Phase B: GEMM+LSTM / GEMM+linear. 3-buffer 2-deep counted-vmcnt
// prefetch pipeline over 32-K panels (unchanged from round 5).
// =====================================================================
struct GArgs {
    const u16* A1; const u16* A2;
    const u16 *B1, *B2;
    const float* bias;
    const u16* c_in; u16* cout_b;
    u16* h_out;
    u16* lin_out;
    int KP1, KP2;          // panels (K/32) per seg; 0 = absent
    int as1, as2;          // A tile stride (elements)
    int mode;
};

// Phase-B LDS: 3 x (8KB A panel + 8KB B panel) = 48KB; sG aliases.
union SMemB {
    u16 st[3][2][4096];
    float g[32][132];
};

// persistent LSTM-step GEMM: 768 blocks (3/CU), tn=bx&31, 4 tm tiles each
__global__ __launch_bounds__(256, 3) void gemm_lstm(GArgs g)
{
    __shared__ SMemB sm;
    const int tid = threadIdx.x;
    const int wave = tid >> 6, lane = tid & 63;
    const int wm = wave >> 1, wn = wave & 1;
    const int quad = lane >> 4, lc = lane & 15;
    const int tn = blockIdx.x & 31;
    const int tm0 = (blockIdx.x >> 5) * 4;
    const int frA = wm * 2048 + (quad * 16 + lc) * 8;   // + i*512 (panel-packed)
    const int frB = wn * 2048 + (quad * 16 + lc) * 8;   // + j*512

    const u16* B1p = g.B1 + (size_t)tn * g.KP1 * 4096;
    const u16* B2p = g.B2 + (size_t)tn * g.KP2 * 4096;
    const int NP = g.KP1 + g.KP2;

    for (int t = 0; t < 4; ++t) {
        const int tm = tm0 + t;
        const u16* A1t = g.A1 + (size_t)tm * g.as1;
        const u16* A2t = g.A2 + (size_t)tm * g.as2;

        auto issue = [&](int q, int buf) {
            const u16 *Ab, *Bb; int qq;
            if (q < g.KP1) { Ab = A1t; Bb = B1p; qq = q; }
            else           { Ab = A2t; Bb = B2p; qq = q - g.KP1; }
#pragma unroll
            for (int c2 = 0; c2 < 2; ++c2) {
                int cp = wave * 2 + c2;
                size_t go = pgoff(qq, cp, lane);
                gl2lds16(Ab + go, &sm.st[buf][0][cp * 512]);
                gl2lds16(Bb + go, &sm.st[buf][1][cp * 512]);
            }
        };

        f32x4 acc[4][4];
#pragma unroll
        for (int j = 0; j < 4; ++j) {
            float bvx = g.bias[tn * 128 + wn * 64 + j * 16 + lc];
            f32x4 bvv = {bvx, bvx, bvx, bvx};
#pragma unroll
            for (int i = 0; i < 4; ++i) acc[i][j] = bvv;
        }

        issue(0, 0);
        issue(1, 1);
        for (int q = 0; q < NP; ++q) {
            if (q + 1 < NP) asm volatile("s_waitcnt vmcnt(4)" ::: "memory");
            else            asm volatile("s_waitcnt vmcnt(0)" ::: "memory");
            __builtin_amdgcn_s_barrier();    // all waves: landed + done MFMA(q-1)
            __builtin_amdgcn_sched_barrier(0);
            if (q + 2 < NP) issue(q + 2, (q + 2) % 3);
            const u16* la = sm.st[q % 3][0];
            const u16* lb = sm.st[q % 3][1];
            bf16x8 aF[4], bF[4];
#pragma unroll
            for (int i = 0; i < 4; ++i)
                aF[i] = *(const bf16x8*)&la[frA + i * 512];
#pragma unroll
            for (int j = 0; j < 4; ++j)
                bF[j] = *(const bf16x8*)&lb[frB + j * 512];
#pragma unroll
            for (int i = 0; i < 4; ++i)
#pragma unroll
                for (int j = 0; j < 4; ++j)
                    acc[i][j] = __builtin_amdgcn_mfma_f32_16x16x32_bf16(aF[i], bF[j], acc[i][j], 0, 0, 0);
        }
        __syncthreads();   // all MFMA reads done; sG (aliases st) now writable

        const int rl = tid >> 3, ub = (tid & 7) * 4;
#pragma unroll 1
        for (int i = 0; i < 4; ++i) {
#pragma unroll
            for (int j = 0; j < 4; ++j)
#pragma unroll
                for (int r = 0; r < 4; ++r)
                    sG_alias: ;
            // (label removed by compiler; loop body below)
#pragma unroll
            for (int j = 0; j < 4; ++j)
#pragma unroll
                for (int r = 0; r < 4; ++r)
                    sm.g[wm * 16 + quad * 4 + r][wn * 64 + j * 16 + lc] = acc[i][j][r];
            __syncthreads();
            int lrow = (rl >> 4) * 64 + i * 16 + (rl & 15);
            size_t pOff = (size_t)tm * SLOTE + ((size_t)tn * 128 + lrow) * 32 + ub;
            ushort4 co = *(const ushort4*)(g.c_in + pOff);
            float cold[4] = {bf2f(co.x), bf2f(co.y), bf2f(co.z), bf2f(co.w)};
            float c2v[4], h2v[4];
#pragma unroll
            for (int uu = 0; uu < 4; ++uu) {
                float4 gg = *(const float4*)&sm.g[rl][(ub + uu) * 4];
                float iv = fsig(gg.x), fv = fsig(gg.y), gv = ftanh(gg.z), ov = fsig(gg.w);
                float c2 = fv * cold[uu] + iv * gv;
                c2v[uu] = c2;
                h2v[uu] = ov * ftanh(c2);
            }
            *(ushort4*)(g.cout_b + pOff) =
                make_ushort4(f2bf(c2v[0]), f2bf(c2v[1]), f2bf(c2v[2]), f2bf(c2v[3]));
            *(ushort4*)(g.h_out + (size_t)tm * SLOTE + fmoff(lrow, tn * 32 + ub)) =
                make_ushort4(f2bf(h2v[0]), f2bf(h2v[1]), f2bf(h2v[2]), f2bf(h2v[3]));
            __syncthreads();
        }
    }
}

// linear-head GEMM: grid = 96 blocks (one per sample tile), tn = 0
__global__ __launch_bounds__(256, 3) void gemm_lin(GArgs g)
{
    __shared__ u16 st[3][2][4096];
    const int tid = threadIdx.x;
    const int wave = tid >> 6, lane = tid & 63;
    const int wm = wave >> 1, wn = wave & 1;
    const int quad = lane >> 4, lc = lane & 15;
    const int tm = blockIdx.x;
    const int frA = wm * 2048 + (quad * 16 + lc) * 8;
    const int frB = wn * 2048 + (quad * 16 + lc) * 8;

    const u16* A1t = g.A1 + (size_t)tm * g.as1;
    const int NP = g.KP1;

    auto issue = [&](int q, int buf) {
#pragma unroll
        for (int c2 = 0; c2 < 2; ++c2) {
            int cp = wave * 2 + c2;
            size_t go = pgoff(q, cp, lane);
            gl2lds16(A1t + go, &st[buf][0][cp * 512]);
            gl2lds16(g.B1 + go, &st[buf][1][cp * 512]);
        }
    };

    f32x4 acc[4][4];
#pragma unroll
    for (int j = 0; j < 4; ++j) {
        float bvx = g.bias[wn * 64 + j * 16 + lc];
        f32x4 bvv = {bvx, bvx, bvx, bvx};
#pragma unroll
        for (int i = 0; i < 4; ++i) acc[i][j] = bvv;
    }

    issue(0, 0);
    issue(1, 1);
    for (int q = 0; q < NP; ++q) {
        if (q + 1 < NP) asm volatile("s_waitcnt vmcnt(4)" ::: "memory");
        else            asm volatile("s_waitcnt vmcnt(0)" ::: "memory");
        __builtin_amdgcn_s_barrier();
        __builtin_amdgcn_sched_barrier(0);
        if (q + 2 < NP) issue(q + 2, (q + 2) % 3);
        const u16* la = st[q % 3][0];
        const u16* lb = st[q % 3][1];
        bf16x8 aF[4], bF[4];
#pragma unroll
        for (int i = 0; i < 4; ++i)
            aF[i] = *(const bf16x8*)&la[frA + i * 512];
#pragma unroll
        for (int j = 0; j < 4; ++j)
            bF[j] = *(const bf16x8*)&lb[frB + j * 512];
#pragma unroll
        for (int i = 0; i < 4; ++i)
#pragma unroll
            for (int j = 0; j < 4; ++j)
                acc[i][j] = __builtin_amdgcn_mfma_f32_16x16x32_bf16(aF[i], bF[j], acc[i][j], 0, 0, 0);
    }

    // pred tile in FM layout
#pragma unroll
    for (int i = 0; i < 4; ++i)
#pragma unroll
        for (int j = 0; j < 4; ++j)
#pragma unroll
            for (int r = 0; r < 4; ++r) {
                int grow = wm * 64 + i * 16 + quad * 4 + r;
                int gcol = wn * 64 + j * 16 + lc;
                g.lin_out[(size_t)tm * PREDT + fmoff(grow, gcol)] = f2bf(acc[i][j][r]);
            }
}

// ---- setup / epilogue kernels ----
__global__ void convert_weight(const float* __restrict__ src, u16* __restrict__ dst,
                               int kshift, int permute, int total) {
    int idx = blockIdx.x * 256 + threadIdx.x;
    if (idx >= total) return;
    const int K = 1 << kshift;
    int kk = idx & (K - 1);
    int rr = (idx >> kshift) & 127;
    int s = idx >> (kshift + 7);
    int jp = s * 128 + rr;
    int srow = permute ? ((jp & 3) * HID + (jp >> 2)) : jp;
    dst[((size_t)s << (kshift + 7)) + fmoff(rr, kk)] =
        f2bf(src[((size_t)srow << kshift) + kk]);
}

__global__ void conv_input(const float* __restrict__ in, u16* __restrict__ inb) {
    int idx = blockIdx.x * 256 + threadIdx.x;  // 96*128*128
    int f = idx & 127;
    int b = (idx >> 7) & 127;
    int k = idx >> 14;
    inb[(size_t)k * PREDT + fmoff(b, f)] = f2bf(in[idx]);
}

__global__ void combine_bias(const float* __restrict__ bi, const float* __restrict__ bh,
                             float* __restrict__ dst) {
    int j = blockIdx.x * 256 + threadIdx.x;  // 4096
    int s = (j & 3) * HID + (j >> 2);
    dst[j] = bi[s] + bh[s];
}

__global__ void init_state(const float* __restrict__ h0, u16* __restrict__ chainH) {
    int idx = blockIdx.x * 256 + threadIdx.x;  // 2*BAT*HID
    int l = idx >> 17;
    int r = idx & (int)(SLOTE - 1);
    int b = r >> 10, hh = r & 1023;
    chainH[(size_t)l * 97 * SLOTE + fmoff(b, hh)] = f2bf(h0[idx]);
}

__global__ void init_flags(int* __restrict__ f) {
    int gid = blockIdx.x * 256 + threadIdx.x;
    if (gid >= FLAGN) return;
    int step = (gid >> 10) % 97;             // flag word stride 32 ints; 32 blocks/step
    f[gid] = ((gid & 31) == 0 && step == 0) ? 1 : 0;
}

__global__ void copy_next(const u16* __restrict__ predsb, float* __restrict__ out) {
    int idx = blockIdx.x * 256 + threadIdx.x;  // BAT*FEAT
    int b = idx >> 7, f = idx & 127;
    out[idx] = bf2f(predsb[(size_t)95 * PREDT + fmoff(b, f)]);
}

__global__ void gather_out(const float* __restrict__ inMusic, const u16* __restrict__ predsb,
                           float* __restrict__ outM) {
    int idx = blockIdx.x * 256 + threadIdx.x;  // 96*128*128*8
    int n = idx & 7;
    int f = (idx >> 3) & 127;
    int b = (idx >> 10) & 127;
    int r = idx >> 17;
    float v = 0.0f;
    if (r < NPRED && n >= r) {
        v = inMusic[((size_t)r * BAT + b) * FEAT + f];
    } else {
        int k = r - n - 1;
        if (n < k)
            v = bf2f(predsb[((size_t)n * NSAMP + k) * PREDT + fmoff(b, f)]);
    }
    outM[idx] = v;
}

__global__ void zero_out(float* __restrict__ o, int nmax) {
    int idx = blockIdx.x * 256 + threadIdx.x;
    if (idx < nmax) o[idx] = 0.0f;
}

extern "C" void kernel_launch(void* const* d_in, const int* in_sizes, int n_in,
                              void* d_out, int out_size, void* d_ws, size_t ws_size,
                              hipStream_t stream) {
    (void)in_sizes; (void)n_in;
    const float* inMusic = (const float*)d_in[0];
    const float* h0   = (const float*)d_in[1];
    const float* c0   = (const float*)d_in[2];
    const float* Wih0 = (const float*)d_in[3];
    const float* Whh0 = (const float*)d_in[4];
    const float* bih0 = (const float*)d_in[5];
    const float* bhh0 = (const float*)d_in[6];
    const float* Wih1 = (const float*)d_in[7];
    const float* Whh1 = (const float*)d_in[8];
    const float* bih1 = (const float*)d_in[9];
    const float* bhh1 = (const float*)d_in[10];
    const float* Wlin = (const float*)d_in[11];
    const float* blin = (const float*)d_in[12];
    float* out = (float*)d_out;

    const size_t OUT_H = (size_t)NSAMP * BAT * FEAT * NPRED;
    const size_t OUT_C = OUT_H + 2 * SLOTE;
    const size_t OUT_NEXT = OUT_C + 2 * SLOTE;

    char* ws = (char*)d_ws;
    size_t off = 0;
    auto alloc = [&](size_t bytes) {
        void* p = ws + off;
        off = (off + bytes + 255) & ~(size_t)255;
        return p;
    };
    u16* Wih0p = (u16*)alloc((size_t)GD * FEAT * 2);
    u16* Whh0p = (u16*)alloc((size_t)GD * HID * 2);
    u16* Wih1p = (u16*)alloc((size_t)GD * HID * 2);
    u16* Whh1p = (u16*)alloc((size_t)GD * HID * 2);
    u16* Wlinb = (u16*)alloc((size_t)FEAT * HID * 2);
    float* bp0 = (float*)alloc(GD * 4);
    float* bp1 = (float*)alloc(GD * 4);
    u16* chainH  = (u16*)alloc((size_t)2 * 97 * SLOTE * 2);
    u16* chainCb = (u16*)alloc((size_t)2 * 97 * SLOTE * 2);
    u16* hp2 = (u16*)alloc((size_t)2 * (size_t)NSAMP * SLOTE * 2);
    u16* predsb = (u16*)alloc((size_t)NPRED * NSAMP * PREDT * 2);
    u16* inb = (u16*)alloc((size_t)NSAMP * PREDT * 2);
    int* flags = (int*)alloc((size_t)FLAGN * 4);

    if (off > ws_size) {
        zero_out<<<(out_size + 255) / 256, 256, 0, stream>>>(out, out_size);
        return;
    }

    convert_weight<<<(GD * FEAT + 255) / 256, 256, 0, stream>>>(Wih0, Wih0p, 7, 1, GD * FEAT);
    convert_weight<<<(GD * HID + 255) / 256, 256, 0, stream>>>(Whh0, Whh0p, 10, 1, GD * HID);
    convert_weight<<<(GD * HID + 255) / 256, 256, 0, stream>>>(Wih1, Wih1p, 10, 1, GD * HID);
    convert_weight<<<(GD * HID + 255) / 256, 256, 0, stream>>>(Whh1, Whh1p, 10, 1, GD * HID);
    convert_weight<<<(FEAT * HID + 255) / 256, 256, 0, stream>>>(Wlin, Wlinb, 10, 0, FEAT * HID);
    conv_input<<<(NSAMP * BAT * FEAT) / 256, 256, 0, stream>>>(inMusic, inb);
    combine_bias<<<GD / 256, 256, 0, stream>>>(bih0, bhh0, bp0);
    combine_bias<<<GD / 256, 256, 0, stream>>>(bih1, bhh1, bp1);
    init_state<<<(int)(2 * SLOTE) / 256, 256, 0, stream>>>(h0, chainH);
    init_flags<<<(FLAGN + 255) / 256, 256, 0, stream>>>(flags);

    lstm_chain<<<64, 256, 0, stream>>>(
        inb, Wih0p, Whh0p, Wih1p, Whh1p, bp0, bp1, c0,
        chainH, chainCb, out + OUT_H, out + OUT_C, flags);

    auto Hs = [&](int l, int s) { return chainH + ((size_t)l * 97 + s) * SLOTE; };
    auto Cs = [&](int l, int s) { return chainCb + ((size_t)l * 97 + s) * SLOTE; };

    u16* hbuf0[2] = {Hs(0, 1), Hs(1, 1)};
    u16* hbuf1[2] = {hp2, hp2 + (size_t)NSAMP * SLOTE};
    u16* cB[2] = {Cs(0, 1), Cs(1, 1)};

    auto mkLin = [&](const u16* src, u16* dst) {
        GArgs a = {};
        a.A1 = src; a.KP1 = 32; a.as1 = (int)SLOTE; a.KP2 = 0;
        a.B1 = Wlinb; a.bias = blin;
        a.lin_out = dst; a.mode = 1;
        return a;
    };
    auto mkB = [&](int l, const u16* A1, int kp1, int as1, const u16* A2, u16* nxt) {
        GArgs a = {};
        a.A1 = A1; a.KP1 = kp1; a.as1 = as1;
        a.A2 = A2; a.KP2 = 32; a.as2 = (int)SLOTE;
        a.B1 = (l == 0) ? Wih0p : Wih1p; a.B2 = (l == 0) ? Whh0p : Whh1p;
        a.bias = (l == 0) ? bp0 : bp1;
        a.c_in = cB[l]; a.cout_b = cB[l];
        a.h_out = nxt; a.mode = 0;
        return a;
    };

    gemm_lin<<<96, 256, 0, stream>>>(mkLin(hbuf0[1], predsb));
    copy_next<<<(BAT * FEAT) / 256, 256, 0, stream>>>(predsb, out + OUT_NEXT);

    for (int n = 1; n < NPRED; ++n) {
        u16* cur0 = (n & 1) ? hbuf0[0] : hbuf1[0];
        u16* cur1 = (n & 1) ? hbuf0[1] : hbuf1[1];
        u16* nxt0 = (n & 1) ? hbuf1[0] : hbuf0[0];
        u16* nxt1 = (n & 1) ? hbuf1[1] : hbuf0[1];
        const u16* pin = predsb + (size_t)(n - 1) * NSAMP * PREDT;
        u16* pout = predsb + (size_t)n * NSAMP * PREDT;
        gemm_lstm<<<768, 256, 0, stream>>>(mkB(0, pin, 4, PREDT, cur0, nxt0));
        gemm_lstm<<<768, 256, 0, stream>>>(mkB(1, nxt0, 32, (int)SLOTE, cur1, nxt1));
        gemm_lin<<<96, 256, 0, stream>>>(mkLin(nxt1, pout));
    }

    gather_out<<<(NSAMP * BAT * FEAT * NPRED) / 256, 256, 0, stream>>>(inMusic, predsb, out);
}